// Round 6
// baseline (3785.635 us; speedup 1.0000x reference)
//
#include <hip/hip_runtime.h>
#include <hip/hip_cooperative_groups.h>
#include <math.h>

namespace cg = cooperative_groups;

// Problem constants
constexpr int NB  = 1024;   // batch
constexpr int NL  = 96;     // seq len L
constexpr int ND  = 128;    // D
constexpr int NHS = 512;    // hidden
constexpr int NT  = 24;     // timesteps
constexpr int NN  = 128;    // attention dim N
constexpr int NG4 = 4 * NHS; // 2048
constexpr int NK  = ND + NHS; // 640 concat K
constexpr int BL  = NB * NL; // 98304

typedef __attribute__((ext_vector_type(8))) short bf16x8;
typedef __attribute__((ext_vector_type(4))) float f32x4;

static __device__ __forceinline__ unsigned short f2b(float x) {
    union { float f; unsigned u; } v; v.f = x;
    unsigned r = v.u + 0x7fffu + ((v.u >> 16) & 1u);   // RNE
    return (unsigned short)(r >> 16);
}
static __device__ __forceinline__ float b2f(unsigned short s) {
    union { unsigned u; float f; } v; v.u = ((unsigned)s) << 16;
    return v.f;
}

// fast transcendentals: exp2-based, inf-safe saturation
constexpr float LOG2E  = 1.4426950408889634f;
static __device__ __forceinline__ float fast_exp(float x) {
    return __builtin_amdgcn_exp2f(x * LOG2E);
}
static __device__ __forceinline__ float fast_tanh(float x) {
    float e2 = __builtin_amdgcn_exp2f(x * (2.0f * LOG2E));   // e^{2x}
    return 1.0f - 2.0f * __builtin_amdgcn_rcpf(1.0f + e2);
}
static __device__ __forceinline__ float fast_sigmoid(float x) {
    float e = __builtin_amdgcn_exp2f(-x * LOG2E);
    return __builtin_amdgcn_rcpf(1.0f + e);
}

// ---------------------------------------------------------------- init state
__global__ __launch_bounds__(256) void k_init(const float* __restrict__ emb,
                                              const float* __restrict__ y0,
                                              float* __restrict__ c,
                                              unsigned short* __restrict__ Ab0,
                                              float* __restrict__ y) {
    int idx = blockIdx.x * blockDim.x + threadIdx.x;
    if (idx < NB * NHS) {
        int b = idx / NHS, s = idx - b * NHS;
        Ab0[(size_t)b * NK + ND + s] = f2b(emb[b * 2 * NHS + s]);
        c[idx] = emb[b * 2 * NHS + NHS + s];
    }
    if (idx < NB) y[idx] = y0[idx];
}

// ---------------------------------------------------------------- H -> bf16
__global__ __launch_bounds__(256) void k_prep(const float* __restrict__ H,
                                              unsigned short* __restrict__ Hbf) {
    int idx = (blockIdx.x * 256 + threadIdx.x) * 8;
    float4 a = *(const float4*)(H + idx);
    float4 b = *(const float4*)(H + idx + 4);
    bf16x8 o;
    o[0] = (short)f2b(a.x); o[1] = (short)f2b(a.y);
    o[2] = (short)f2b(a.z); o[3] = (short)f2b(a.w);
    o[4] = (short)f2b(b.x); o[5] = (short)f2b(b.y);
    o[6] = (short)f2b(b.z); o[7] = (short)f2b(b.w);
    *(bf16x8*)(Hbf + idx) = o;
}

// ---------------------------------------------------------------- Wa -> bf16, [t][n][d] layout
__global__ __launch_bounds__(128) void k_prepwa(const float* __restrict__ Wa,
                                                unsigned short* __restrict__ Wab) {
    int tn = blockIdx.x;          // t*NN + n
    int t = tn / NN, n = tn - t * NN;
    int d = threadIdx.x;
    Wab[(size_t)tn * ND + d] = f2b(Wa[(size_t)d * (NT * NN) + t * NN + n]);
}

// ---------------------------------------------------------------- W,U -> bf16 Wg[t][kb][n][64]
__global__ __launch_bounds__(256) void k_prepw(const float* __restrict__ W,
                                               const float* __restrict__ U,
                                               unsigned short* __restrict__ Wg) {
    __shared__ unsigned short ts[64][66];
    int nc = blockIdx.x;    // 0..31
    int kc = blockIdx.y;    // 0..9  (= kb)
    int t  = blockIdx.z;    // 0..23
    int tid = threadIdx.x;
    int rowt = tid >> 4;         // 0..15
    int n4   = (tid & 15) << 2;  // 0..60 step 4
#pragma unroll
    for (int i = 0; i < 4; ++i) {
        int kl = i * 16 + rowt;
        int k  = kc * 64 + kl;
        const float* src = (k < ND) ? (W + (size_t)k * (NT * NG4))
                                    : (U + (size_t)(k - ND) * (NT * NG4));
        float4 v = *(const float4*)&src[t * NG4 + nc * 64 + n4];
        ts[kl][n4 + 0] = f2b(v.x);
        ts[kl][n4 + 1] = f2b(v.y);
        ts[kl][n4 + 2] = f2b(v.z);
        ts[kl][n4 + 3] = f2b(v.w);
    }
    __syncthreads();
    size_t base = (((size_t)t * 10 + kc) * NG4 + nc * 64) * 64;
#pragma unroll
    for (int p = 0; p < 2; ++p) {
        int flat = p * 256 + tid;
        int nl = flat >> 3, k8 = (flat & 7) << 3;
        bf16x8 o;
#pragma unroll
        for (int j = 0; j < 8; ++j) o[j] = (short)ts[k8 + j][nl];
        *(bf16x8*)&Wg[base + (size_t)nl * 64 + k8] = o;
    }
}

// ---------------------------------------------------------------- step-0 cua partials
__global__ __launch_bounds__(256) void k_cua0(const float* __restrict__ c,
                                              const float* __restrict__ Ua,
                                              float* __restrict__ cua_part) {
    __shared__ float cs[16][132];
    int m0 = blockIdx.x * 16, n0 = blockIdx.y;
    int tid = threadIdx.x;
#pragma unroll
    for (int i = 0; i < 8; ++i) {
        int idx = tid + i * 256;
        int row = idx >> 7, k = idx & 127;
        cs[row][k] = c[(size_t)(m0 + row) * NHS + n0 * 128 + k];
    }
    __syncthreads();
    int n = tid & 127, rg = tid >> 7;
    float a8[8] = {0, 0, 0, 0, 0, 0, 0, 0};
    for (int k = 0; k < 128; ++k) {
        float ua = Ua[(size_t)(n0 * 128 + k) * (NT * NN) + n];  // t = 0
#pragma unroll
        for (int i = 0; i < 8; ++i) a8[i] += cs[rg * 8 + i][k] * ua;
    }
#pragma unroll
    for (int i = 0; i < 8; ++i)
        cua_part[((size_t)(m0 + rg * 8 + i) * 4 + n0) * 128 + n] = a8[i];
}

// ---------------------------------------------------------------- persistent cooperative sequence kernel
// 256 blocks x 512 threads, 1 block/CU. Per t: phase A (attention, 4 b per block)
// -> grid sync -> phase B (gates GEMM + cell, 16 rows x 128-col slice) -> grid sync.
__global__ __launch_bounds__(512, 2) void k_seq(
        const unsigned short* __restrict__ Hbf,
        const unsigned short* __restrict__ Wab,
        const float* __restrict__ Va,
        const float* __restrict__ ba,
        const float* __restrict__ bias,
        const float* __restrict__ Wy,
        const float* __restrict__ fcw,
        const float* __restrict__ fcb,
        const float* __restrict__ Ua,
        const unsigned short* __restrict__ Wg,
        float* __restrict__ c,
        float* __restrict__ y_st,
        float* __restrict__ y_part,
        float* __restrict__ cua_part,
        unsigned short* __restrict__ Ab0,
        unsigned short* __restrict__ Ab1,
        float* __restrict__ out_y,
        float* __restrict__ out_h) {
    cg::grid_group gg = cg::this_grid();
    __shared__ __align__(16) char pool[73728];   // Ws (A) / Bst+gs+cs (B)
    __shared__ float sc4[4][NL];
    __shared__ float cua_s4[4][NN];
    __shared__ float yredL[16][2];

    int blk = blockIdx.x;
    int tid = threadIdx.x;
    int lane = tid & 63, wave = tid >> 6;
    int ln = lane & 15, kg = lane >> 4;
    int b0 = blk * 4;
    const float scale_c = 0.044194173824159216f;  // 1/sqrt(512)
    f32x4 zero = {0.f, 0.f, 0.f, 0.f};

    for (int t = 0; t < NT; ++t) {
        unsigned short* AbC = (t & 1) ? Ab1 : Ab0;   // current [ht|h]
        unsigned short* AbN = (t & 1) ? Ab0 : Ab1;   // next h

        // ================= Phase A: attention for b0..b0+3 =================
        {
            unsigned short* Ws = (unsigned short*)pool;   // [128][136]
            const unsigned short* src = Wab + (size_t)t * NN * ND;
#pragma unroll
            for (int f = 0; f < 4; ++f) {
                int idx = tid + f * 512;
                int n = idx >> 4, d0 = (idx & 15) << 3;
                *(bf16x8*)&Ws[n * 136 + d0] = *(const bf16x8*)(src + n * ND + d0);
            }
            {
                int bl = tid >> 7, n = tid & 127;
                const float* cp = cua_part + (size_t)(b0 + bl) * 512 + n;
                cua_s4[bl][n] = cp[0] + cp[128] + cp[256] + cp[384] + ba[t * NN + n];
            }
            if (t > 0 && tid < 4) {
                int b = b0 + tid;
                const float* yp = y_part + (size_t)b * 4;
                float yv = fcb[t - 1] + yp[0] + yp[1] + yp[2] + yp[3];
                y_st[b] = yv;
                out_y[b * NT + (t - 1)] = yv;
            }
            __syncthreads();

            float va_l[8];
#pragma unroll
            for (int nt = 0; nt < 8; ++nt) va_l[nt] = Va[(nt * 16 + ln) * NT + t];

#pragma unroll
            for (int ti = 0; ti < 3; ++ti) {
                int tau = wave + ti * 8;              // 0..23
                int bl = tau / 6, r0 = (tau % 6) * 16;
                const unsigned short* Hrow = Hbf + ((size_t)(b0 + bl) * NL + r0 + ln) * ND;
                f32x4 acc[8];
#pragma unroll
                for (int nt = 0; nt < 8; ++nt) acc[nt] = zero;
#pragma unroll
                for (int kc = 0; kc < 4; ++kc) {
                    int d0 = kc * 32 + kg * 8;
                    bf16x8 a = *(const bf16x8*)(Hrow + d0);
#pragma unroll
                    for (int nt = 0; nt < 8; ++nt) {
                        bf16x8 bb = *(const bf16x8*)&Ws[(nt * 16 + ln) * 136 + d0];
                        acc[nt] = __builtin_amdgcn_mfma_f32_16x16x32_bf16(a, bb, acc[nt], 0, 0, 0);
                    }
                }
#pragma unroll
                for (int r = 0; r < 4; ++r) {
                    float s = 0.f;
#pragma unroll
                    for (int nt = 0; nt < 8; ++nt) {
                        float pre = acc[nt][r] + cua_s4[bl][nt * 16 + ln];
                        s += va_l[nt] * fast_tanh(pre);
                    }
#pragma unroll
                    for (int off = 1; off < 16; off <<= 1) s += __shfl_xor(s, off);
                    if (ln == 0) sc4[bl][r0 + kg * 4 + r] = s * scale_c;
                }
            }
            __syncthreads();

            if (wave < 4) {           // softmax for b_local = wave over 96 scores
                float s0 = sc4[wave][lane];
                float s1 = (lane < 32) ? sc4[wave][64 + lane] : -1e30f;
                float m = fmaxf(s0, s1);
#pragma unroll
                for (int off = 32; off; off >>= 1) m = fmaxf(m, __shfl_xor(m, off));
                float p0 = fast_exp(s0 - m);
                float p1 = (lane < 32) ? fast_exp(s1 - m) : 0.f;
                float ssum = p0 + p1;
#pragma unroll
                for (int off = 32; off; off >>= 1) ssum += __shfl_xor(ssum, off);
                float inv = __builtin_amdgcn_rcpf(ssum);
                sc4[wave][lane] = p0 * inv;
                if (lane < 32) sc4[wave][64 + lane] = p1 * inv;
            }
            __syncthreads();

            {   // context: 4 b x 128 d, one thread per (b,d)
                int bl = tid >> 7, dd = tid & 127;
                const unsigned short* Hb = Hbf + (size_t)(b0 + bl) * NL * ND;
                float a0 = 0.f;
                for (int l = 0; l < NL; ++l)
                    a0 += sc4[bl][l] * b2f(Hb[(size_t)l * ND + dd]);
                AbC[(size_t)(b0 + bl) * NK + dd] = f2b(a0);
            }
        }
        gg.sync();

        // ================= Phase B: gates GEMM + cell =================
        {
            int m0 = (blk >> 2) * 16, n0 = blk & 3;
            int g = wave >> 1, nh = wave & 1;       // gate, 64-col half
            unsigned short* Bst = (unsigned short*)pool;    // [4][128][72]
            const unsigned short* Arow = AbC + (size_t)(m0 + ln) * NK;
            f32x4 acc[4];
#pragma unroll
            for (int nt = 0; nt < 4; ++nt) acc[nt] = zero;

            for (int kb = 0; kb < 10; ++kb) {
                const unsigned short* Wkb = Wg +
                    (((size_t)(t * 10 + kb)) * NG4 + g * NHS + n0 * 128 + nh * 64) * 64;
                unsigned short* dst = Bst + (size_t)(g * 128 + nh * 64) * 72;
#pragma unroll
                for (int i = 0; i < 8; ++i) {       // wave-private 64n x 64k stage
                    int flat = i * 64 + lane;
                    int n = flat >> 3, k8 = (flat & 7) << 3;
                    *(bf16x8*)&dst[n * 72 + k8] = *(const bf16x8*)(Wkb + (size_t)n * 64 + k8);
                }
#pragma unroll
                for (int kc = 0; kc < 2; ++kc) {
                    int d0 = kc * 32 + kg * 8;
                    bf16x8 a = *(const bf16x8*)(Arow + kb * 64 + d0);
#pragma unroll
                    for (int nt = 0; nt < 4; ++nt) {
                        bf16x8 bb = *(const bf16x8*)&dst[(nt * 16 + ln) * 72 + d0];
                        acc[nt] = __builtin_amdgcn_mfma_f32_16x16x32_bf16(a, bb, acc[nt], 0, 0, 0);
                    }
                }
            }
            __syncthreads();

            float* gs = (float*)pool;                    // [4][16][132]
            float* cs = (float*)(pool + 33792);          // [16][132]
#pragma unroll
            for (int nt = 0; nt < 4; ++nt)
#pragma unroll
                for (int r = 0; r < 4; ++r)
                    gs[g * 2112 + (kg * 4 + r) * 132 + nh * 64 + nt * 16 + ln] = acc[nt][r];
            __syncthreads();

            int s_loc = tid & 127, rg4 = tid >> 7;
            int s_glob = n0 * 128 + s_loc;
            float bi0 = bias[t * NG4 + s_glob];
            float bi1 = bias[t * NG4 + NHS + s_glob];
            float bi2 = bias[t * NG4 + 2 * NHS + s_glob];
            float bi3 = bias[t * NG4 + 3 * NHS + s_glob];
            float wy0 = Wy[t * NG4 + s_glob];
            float wy1 = Wy[t * NG4 + NHS + s_glob];
            float wy2 = Wy[t * NG4 + 2 * NHS + s_glob];
            float wy3 = Wy[t * NG4 + 3 * NHS + s_glob];
            float fw  = fcw[t * NHS + s_glob];
            float prow[4];
#pragma unroll
            for (int i = 0; i < 4; ++i) {
                int row = rg4 * 4 + i;
                int b = m0 + row;
                float yp = y_st[b];
                float gi  = gs[0 * 2112 + row * 132 + s_loc] + bi0 + yp * wy0;
                float gf  = gs[1 * 2112 + row * 132 + s_loc] + bi1 + yp * wy1;
                float gg2 = gs[2 * 2112 + row * 132 + s_loc] + bi2 + yp * wy2;
                float go  = gs[3 * 2112 + row * 132 + s_loc] + bi3 + yp * wy3;
                float iv = fast_sigmoid(gi);
                float fv = fast_sigmoid(gf);
                float gv = fast_tanh(gg2);
                float ov = fast_sigmoid(go);
                float cn = fv * c[(size_t)b * NHS + s_glob] + iv * gv;
                float hn = ov * fast_tanh(cn);
                c[(size_t)b * NHS + s_glob] = cn;
                cs[row * 132 + s_loc] = cn;
                AbN[(size_t)b * NK + ND + s_glob] = f2b(hn);
                out_h[(size_t)b * (NT * NHS) + t * NHS + s_glob] = hn;
                prow[i] = hn * fw;
            }
#pragma unroll
            for (int i = 0; i < 4; ++i) {
                float v = prow[i];
#pragma unroll
                for (int off = 32; off; off >>= 1) v += __shfl_xor(v, off);
                if (lane == 0) yredL[rg4 * 4 + i][(tid >> 6) & 1] = v;
            }
            __syncthreads();
            if (tid < 16)
                y_part[(size_t)(m0 + tid) * 4 + n0] = yredL[tid][0] + yredL[tid][1];

            if (t + 1 < NT) {       // cua partial for t+1 from fresh c
                float a4[4] = {0.f, 0.f, 0.f, 0.f};
                int n = s_loc;
                for (int k = 0; k < 128; ++k) {
                    float ua = Ua[(size_t)(n0 * 128 + k) * (NT * NN) + (t + 1) * NN + n];
#pragma unroll
                    for (int i = 0; i < 4; ++i) a4[i] += cs[(rg4 * 4 + i) * 132 + k] * ua;
                }
#pragma unroll
                for (int i = 0; i < 4; ++i)
                    cua_part[((size_t)(m0 + rg4 * 4 + i) * 4 + n0) * 128 + n] = a4[i];
            }
        }
        gg.sync();
    }

    // final y (t = NT-1)
    if (tid < 4) {
        int b = blk * 4 + tid;
        const float* yp = y_part + (size_t)b * 4;
        out_y[b * NT + (NT - 1)] = fcb[NT - 1] + yp[0] + yp[1] + yp[2] + yp[3];
    }
}

// ---------------------------------------------------------------- launcher
extern "C" void kernel_launch(void* const* d_in, const int* in_sizes, int n_in,
                              void* d_out, int out_size, void* d_ws, size_t ws_size,
                              hipStream_t stream) {
    (void)in_sizes; (void)n_in; (void)out_size; (void)ws_size;
    const float* H    = (const float*)d_in[0];
    const float* y0   = (const float*)d_in[1];
    const float* emb  = (const float*)d_in[2];
    const float* Wa   = (const float*)d_in[4];
    const float* Ua   = (const float*)d_in[5];
    const float* ba   = (const float*)d_in[6];
    const float* Va   = (const float*)d_in[7];
    const float* W    = (const float*)d_in[8];
    const float* U    = (const float*)d_in[9];
    const float* bias = (const float*)d_in[10];
    const float* Wy   = (const float*)d_in[11];
    const float* fcw  = (const float*)d_in[12];
    const float* fcb  = (const float*)d_in[13];

    float* out_y = (float*)d_out;              // (B, T)
    float* out_h = out_y + NB * NT;            // (B, T, HS)

    float* ws       = (float*)d_ws;
    float* c_st     = ws;                                   // B*HS
    float* y_st     = c_st + NB * NHS;                      // B
    float* y_part   = y_st + NB;                            // B*4
    float* cua_part = y_part + NB * 4;                      // B*4*128
    unsigned short* Hbf = (unsigned short*)(cua_part + NB * 4 * 128);  // BL*D
    unsigned short* Wab = Hbf + (size_t)BL * ND;            // T*N*D
    unsigned short* Ab0 = Wab + (size_t)NT * NN * ND;       // B*640
    unsigned short* Ab1 = Ab0 + (size_t)NB * NK;            // B*640
    unsigned short* Wg  = Ab1 + (size_t)NB * NK;            // T*10*2048*64

    hipLaunchKernelGGL(k_init, dim3((NB * NHS) / 256), dim3(256), 0, stream,
                       emb, y0, c_st, Ab0, y_st);
    hipLaunchKernelGGL(k_prep, dim3(BL * ND / (256 * 8)), dim3(256), 0, stream, H, Hbf);
    hipLaunchKernelGGL(k_prepwa, dim3(NT * NN), dim3(128), 0, stream, Wa, Wab);
    hipLaunchKernelGGL(k_prepw, dim3(32, 10, 24), dim3(256), 0, stream, W, U, Wg);
    hipLaunchKernelGGL(k_cua0, dim3(64, 4), dim3(256), 0, stream, c_st, Ua, cua_part);

    void* args[] = {
        (void*)&Hbf, (void*)&Wab, (void*)&Va, (void*)&ba, (void*)&bias,
        (void*)&Wy, (void*)&fcw, (void*)&fcb, (void*)&Ua, (void*)&Wg,
        (void*)&c_st, (void*)&y_st, (void*)&y_part, (void*)&cua_part,
        (void*)&Ab0, (void*)&Ab1, (void*)&out_y, (void*)&out_h
    };
    hipLaunchCooperativeKernel(reinterpret_cast<void*>(k_seq),
                               dim3(256), dim3(512), args, 0, stream);
}

// Round 7
// 1304.631 us; speedup vs baseline: 2.9017x; 2.9017x over previous
//
#include <hip/hip_runtime.h>
#include <math.h>

// Problem constants
constexpr int NB  = 1024;   // batch
constexpr int NL  = 96;     // seq len L
constexpr int ND  = 128;    // D
constexpr int NHS = 512;    // hidden
constexpr int NT  = 24;     // timesteps
constexpr int NN  = 128;    // attention dim N
constexpr int NG4 = 4 * NHS; // 2048
constexpr int NK  = ND + NHS; // 640 concat K
constexpr int BL  = NB * NL; // 98304

typedef __attribute__((ext_vector_type(8))) short bf16x8;
typedef __attribute__((ext_vector_type(4))) float f32x4;

static __device__ __forceinline__ unsigned short f2b(float x) {
    union { float f; unsigned u; } v; v.f = x;
    unsigned r = v.u + 0x7fffu + ((v.u >> 16) & 1u);   // RNE
    return (unsigned short)(r >> 16);
}
static __device__ __forceinline__ float b2f(unsigned short s) {
    union { unsigned u; float f; } v; v.u = ((unsigned)s) << 16;
    return v.f;
}

// fast transcendentals: exp2-based, inf-safe saturation
constexpr float LOG2E  = 1.4426950408889634f;
static __device__ __forceinline__ float fast_exp(float x) {
    return __builtin_amdgcn_exp2f(x * LOG2E);
}
static __device__ __forceinline__ float fast_tanh(float x) {
    float e2 = __builtin_amdgcn_exp2f(x * (2.0f * LOG2E));   // e^{2x}
    return 1.0f - 2.0f * __builtin_amdgcn_rcpf(1.0f + e2);
}
static __device__ __forceinline__ float fast_sigmoid(float x) {
    float e = __builtin_amdgcn_exp2f(-x * LOG2E);
    return __builtin_amdgcn_rcpf(1.0f + e);
}

// ---------------------------------------------------------------- init state
__global__ __launch_bounds__(256) void k_init(const float* __restrict__ emb,
                                              const float* __restrict__ y0,
                                              float* __restrict__ c,
                                              unsigned short* __restrict__ Ab0,
                                              float* __restrict__ y) {
    int idx = blockIdx.x * blockDim.x + threadIdx.x;
    if (idx < NB * NHS) {
        int b = idx / NHS, s = idx - b * NHS;
        Ab0[(size_t)b * NK + ND + s] = f2b(emb[b * 2 * NHS + s]);
        c[idx] = emb[b * 2 * NHS + NHS + s];
    }
    if (idx < NB) y[idx] = y0[idx];
}

// ---------------------------------------------------------------- H -> bf16
__global__ __launch_bounds__(256) void k_prep(const float* __restrict__ H,
                                              unsigned short* __restrict__ Hbf) {
    int idx = (blockIdx.x * 256 + threadIdx.x) * 8;
    float4 a = *(const float4*)(H + idx);
    float4 b = *(const float4*)(H + idx + 4);
    bf16x8 o;
    o[0] = (short)f2b(a.x); o[1] = (short)f2b(a.y);
    o[2] = (short)f2b(a.z); o[3] = (short)f2b(a.w);
    o[4] = (short)f2b(b.x); o[5] = (short)f2b(b.y);
    o[6] = (short)f2b(b.z); o[7] = (short)f2b(b.w);
    *(bf16x8*)(Hbf + idx) = o;
}

// ---------------------------------------------------------------- Wa -> bf16, [t][n][d] layout
__global__ __launch_bounds__(128) void k_prepwa(const float* __restrict__ Wa,
                                                unsigned short* __restrict__ Wab) {
    int tn = blockIdx.x;          // t*NN + n
    int t = tn / NN, n = tn - t * NN;
    int d = threadIdx.x;
    Wab[(size_t)tn * ND + d] = f2b(Wa[(size_t)d * (NT * NN) + t * NN + n]);
}

// ---------------------------------------------------------------- W,U -> bf16 Wg[t][kb][n][64]
__global__ __launch_bounds__(256) void k_prepw(const float* __restrict__ W,
                                               const float* __restrict__ U,
                                               unsigned short* __restrict__ Wg) {
    __shared__ unsigned short ts[64][66];
    int nc = blockIdx.x;    // 0..31
    int kc = blockIdx.y;    // 0..9  (= kb)
    int t  = blockIdx.z;    // 0..23
    int tid = threadIdx.x;
    int rowt = tid >> 4;         // 0..15
    int n4   = (tid & 15) << 2;  // 0..60 step 4
#pragma unroll
    for (int i = 0; i < 4; ++i) {
        int kl = i * 16 + rowt;
        int k  = kc * 64 + kl;
        const float* src = (k < ND) ? (W + (size_t)k * (NT * NG4))
                                    : (U + (size_t)(k - ND) * (NT * NG4));
        float4 v = *(const float4*)&src[t * NG4 + nc * 64 + n4];
        ts[kl][n4 + 0] = f2b(v.x);
        ts[kl][n4 + 1] = f2b(v.y);
        ts[kl][n4 + 2] = f2b(v.z);
        ts[kl][n4 + 3] = f2b(v.w);
    }
    __syncthreads();
    size_t base = (((size_t)t * 10 + kc) * NG4 + nc * 64) * 64;
#pragma unroll
    for (int p = 0; p < 2; ++p) {
        int flat = p * 256 + tid;
        int nl = flat >> 3, k8 = (flat & 7) << 3;
        bf16x8 o;
#pragma unroll
        for (int j = 0; j < 8; ++j) o[j] = (short)ts[k8 + j][nl];
        *(bf16x8*)&Wg[base + (size_t)nl * 64 + k8] = o;
    }
}

// ---------------------------------------------------------------- step-0 cua partials
// cua_part[b][p][n] = sum_{k in p-th 64-chunk} c[b,k] * Ua[k,0,n]   (p = 0..7)
__global__ __launch_bounds__(256) void k_cua0(const float* __restrict__ c,
                                              const float* __restrict__ Ua,
                                              float* __restrict__ cua_part) {
    __shared__ float cs[16][64];
    int m0 = blockIdx.x * 16, n0 = blockIdx.y;   // grid (64, 8)
    int tid = threadIdx.x;
#pragma unroll
    for (int i = 0; i < 4; ++i) {
        int idx = tid + i * 256;
        int row = idx >> 6, k = idx & 63;
        cs[row][k] = c[(size_t)(m0 + row) * NHS + n0 * 64 + k];
    }
    __syncthreads();
    int n = tid & 127, bg = tid >> 7;   // bg 0/1 -> 8 rows each
    float a8[8] = {0, 0, 0, 0, 0, 0, 0, 0};
    for (int k = 0; k < 64; ++k) {
        float ua = Ua[(size_t)(n0 * 64 + k) * (NT * NN) + n];  // t = 0
#pragma unroll
        for (int i = 0; i < 8; ++i) a8[i] += cs[bg * 8 + i][k] * ua;
    }
#pragma unroll
    for (int i = 0; i < 8; ++i)
        cua_part[((size_t)(m0 + bg * 8 + i) * 8 + n0) * 128 + n] = a8[i];
}

// ---------------------------------------------------------------- fused attention (one block per b)
__global__ __launch_bounds__(384, 2) void k_attn_fused(
        const unsigned short* __restrict__ Hbf,
        const unsigned short* __restrict__ Wab,
        const float* __restrict__ Va,
        const float* __restrict__ ba,
        const float* __restrict__ cua_part,
        const float* __restrict__ fcb,
        const float* __restrict__ y_part,
        float* __restrict__ y_st,
        float* __restrict__ out_y,
        unsigned short* __restrict__ Ab,     // ping buffer for step t
        int t) {
    __shared__ unsigned short Ws[NN][136];   // 34.8 KB
    __shared__ float sc[NL];
    __shared__ float cua_s[NN];
    __shared__ float red[24][ND];            // 12.3 KB
    int tid = threadIdx.x;
    int b = blockIdx.x;

    // stage Wa[t] (n-major, d contiguous)
    const unsigned short* src = Wab + (size_t)t * NN * ND;
    for (int f = tid; f < 2048; f += 384) {
        int n = f >> 4, d0 = (f & 15) << 3;
        *(bf16x8*)&Ws[n][d0] = *(const bf16x8*)(src + n * ND + d0);
    }
    // sum cua partials (+ba fold)
    if (tid < 128) {
        const float* cp = cua_part + (size_t)b * 8 * 128 + tid;
        float s = ba[t * NN + tid];
#pragma unroll
        for (int p = 0; p < 8; ++p) s += cp[p * 128];
        cua_s[tid] = s;
    }
    // finalize y[t-1]
    if (t > 0 && tid == 383) {
        const float* yp = y_part + (size_t)b * 8;
        float yv = fcb[t - 1];
#pragma unroll
        for (int p = 0; p < 8; ++p) yv += yp[p];
        y_st[b] = yv;
        out_y[b * NT + (t - 1)] = yv;
    }
    __syncthreads();

    // MFMA scores: 6 waves, wave w -> rows 16w..16w+15 of this b
    int lane = tid & 63, wave = tid >> 6;
    int ln = lane & 15, kg = lane >> 4;
    const unsigned short* Hrow = Hbf + ((size_t)b * NL + wave * 16 + ln) * ND;

    f32x4 zero = {0.f, 0.f, 0.f, 0.f};
    f32x4 acc[8];
#pragma unroll
    for (int nt = 0; nt < 8; ++nt) acc[nt] = zero;
#pragma unroll
    for (int kc = 0; kc < 4; ++kc) {
        int d0 = kc * 32 + kg * 8;
        bf16x8 a = *(const bf16x8*)(Hrow + d0);
#pragma unroll
        for (int nt = 0; nt < 8; ++nt) {
            bf16x8 bb = *(const bf16x8*)&Ws[nt * 16 + ln][d0];
            acc[nt] = __builtin_amdgcn_mfma_f32_16x16x32_bf16(a, bb, acc[nt], 0, 0, 0);
        }
    }
    float va_l[8];
#pragma unroll
    for (int nt = 0; nt < 8; ++nt) va_l[nt] = Va[(nt * 16 + ln) * NT + t];
    const float scale = 0.044194173824159216f;  // 1/sqrt(512)
#pragma unroll
    for (int r = 0; r < 4; ++r) {
        float s = 0.f;
#pragma unroll
        for (int nt = 0; nt < 8; ++nt) {
            float pre = acc[nt][r] + cua_s[nt * 16 + ln];
            s += va_l[nt] * fast_tanh(pre);
        }
#pragma unroll
        for (int off = 1; off < 16; off <<= 1) s += __shfl_xor(s, off);
        if (ln == 0) sc[wave * 16 + kg * 4 + r] = s * scale;
    }
    __syncthreads();

    // softmax over 96 (wave 0)
    if (tid < 64) {
        float s0 = sc[tid];
        float s1 = (tid < 32) ? sc[64 + tid] : -1e30f;
        float m = fmaxf(s0, s1);
#pragma unroll
        for (int off = 32; off; off >>= 1) m = fmaxf(m, __shfl_xor(m, off));
        float p0 = fast_exp(s0 - m);
        float p1 = (tid < 32) ? fast_exp(s1 - m) : 0.f;
        float ssum = p0 + p1;
#pragma unroll
        for (int off = 32; off; off >>= 1) ssum += __shfl_xor(ssum, off);
        float inv = __builtin_amdgcn_rcpf(ssum);
        sc[tid] = p0 * inv;
        if (tid < 32) sc[64 + tid] = p1 * inv;
    }
    __syncthreads();

    // context: 24 l-groups x 16 d-chunks
    int dc = tid & 15, lg = tid >> 4;
    int d0 = dc * 8;
    const unsigned short* Hb = Hbf + (size_t)b * NL * ND;
    float a8[8] = {0, 0, 0, 0, 0, 0, 0, 0};
#pragma unroll
    for (int i = 0; i < 4; ++i) {
        int l = lg * 4 + i;
        bf16x8 hv = *(const bf16x8*)(Hb + l * ND + d0);
        float w = sc[l];
#pragma unroll
        for (int j = 0; j < 8; ++j) a8[j] += w * b2f((unsigned short)hv[j]);
    }
#pragma unroll
    for (int j = 0; j < 8; ++j) red[lg][d0 + j] = a8[j];
    __syncthreads();
    if (tid < ND) {
        float accd = 0.f;
#pragma unroll
        for (int g = 0; g < 24; ++g) accd += red[g][tid];
        Ab[(size_t)b * NK + tid] = f2b(accd);
    }
}

// ---------------------------------------------------------------- fused gates GEMM + cell update
// grid (32, 8) x 512 threads: block = 32 rows x 64-s slice (x4 gates = 256 cols).
// No LDS in GEMM: A/B fragments read direct from global (L1/L2-fed).
// wave w -> gate g = w>>1, 32-col half hf = w&1.
__global__ __launch_bounds__(512) void k_gates_cell(
        const unsigned short* __restrict__ Ab,   // read: [ht | h] for step t
        unsigned short* __restrict__ AbN,        // write: h for step t+1
        const unsigned short* __restrict__ Wg,   // [t][kb][n][64]
        const float* __restrict__ bias,
        const float* __restrict__ Wy,
        const float* __restrict__ fcw,
        const float* __restrict__ Ua,
        const float* __restrict__ y_st,
        float* __restrict__ c,
        float* __restrict__ out_h,
        float* __restrict__ y_part,
        float* __restrict__ cua_part,
        int t) {
    __shared__ float gs[4][32][68];   // 34.8 KB: [gate][row][s_loc]
    __shared__ float cs[32][68];      // 8.7 KB: fresh c
    int tid = threadIdx.x;
    int lane = tid & 63, wave = tid >> 6;
    int ln = lane & 15, kg = lane >> 4;
    int m0 = blockIdx.x * 32, n0 = blockIdx.y;
    int g = wave >> 1, hf = wave & 1;
    int cb = g * NHS + n0 * 64 + hf * 32;        // base gate-col for this wave

    const unsigned short* A0 = Ab + (size_t)(m0 + ln) * NK;
    const unsigned short* A1 = Ab + (size_t)(m0 + 16 + ln) * NK;

    f32x4 zero = {0.f, 0.f, 0.f, 0.f};
    f32x4 acc[2][2];
#pragma unroll
    for (int rt = 0; rt < 2; ++rt)
#pragma unroll
        for (int nt = 0; nt < 2; ++nt) acc[rt][nt] = zero;

    for (int kb = 0; kb < 10; ++kb) {
        const unsigned short* Wkb = Wg + ((size_t)(t * 10 + kb) * NG4) * 64;
#pragma unroll
        for (int kc = 0; kc < 2; ++kc) {
            int d0 = kc * 32 + kg * 8;
            bf16x8 a0 = *(const bf16x8*)(A0 + kb * 64 + d0);
            bf16x8 a1 = *(const bf16x8*)(A1 + kb * 64 + d0);
#pragma unroll
            for (int nt = 0; nt < 2; ++nt) {
                bf16x8 bb = *(const bf16x8*)(Wkb + (size_t)(cb + nt * 16 + ln) * 64 + d0);
                acc[0][nt] = __builtin_amdgcn_mfma_f32_16x16x32_bf16(a0, bb, acc[0][nt], 0, 0, 0);
                acc[1][nt] = __builtin_amdgcn_mfma_f32_16x16x32_bf16(a1, bb, acc[1][nt], 0, 0, 0);
            }
        }
    }
    // scatter to gs: col s_loc = hf*32 + nt*16 + ln, row = rt*16 + kg*4 + r
#pragma unroll
    for (int rt = 0; rt < 2; ++rt)
#pragma unroll
        for (int nt = 0; nt < 2; ++nt)
#pragma unroll
            for (int r = 0; r < 4; ++r)
                gs[g][rt * 16 + kg * 4 + r][hf * 32 + nt * 16 + ln] = acc[rt][nt][r];
    __syncthreads();

    // cell update: thread -> s_loc (64), 4 rows (rg = wave)
    int s_loc = tid & 63, rg = tid >> 6;
    int s_glob = n0 * 64 + s_loc;
    float bi0 = bias[t * NG4 + s_glob];
    float bi1 = bias[t * NG4 + NHS + s_glob];
    float bi2 = bias[t * NG4 + 2 * NHS + s_glob];
    float bi3 = bias[t * NG4 + 3 * NHS + s_glob];
    float wy0 = Wy[t * NG4 + s_glob];
    float wy1 = Wy[t * NG4 + NHS + s_glob];
    float wy2 = Wy[t * NG4 + 2 * NHS + s_glob];
    float wy3 = Wy[t * NG4 + 3 * NHS + s_glob];
    float fw  = fcw[t * NHS + s_glob];
    float prow[4];
#pragma unroll
    for (int i = 0; i < 4; ++i) {
        int row = rg * 4 + i;
        int b = m0 + row;
        float yp = y_st[b];
        float gi  = gs[0][row][s_loc] + bi0 + yp * wy0;
        float gf  = gs[1][row][s_loc] + bi1 + yp * wy1;
        float gg2 = gs[2][row][s_loc] + bi2 + yp * wy2;
        float go  = gs[3][row][s_loc] + bi3 + yp * wy3;
        float iv = fast_sigmoid(gi);
        float fv = fast_sigmoid(gf);
        float gv = fast_tanh(gg2);
        float ov = fast_sigmoid(go);
        float cn = fv * c[(size_t)b * NHS + s_glob] + iv * gv;
        float hn = ov * fast_tanh(cn);
        c[(size_t)b * NHS + s_glob] = cn;
        cs[row][s_loc] = cn;
        AbN[(size_t)b * NK + ND + s_glob] = f2b(hn);
        out_h[(size_t)b * (NT * NHS) + t * NHS + s_glob] = hn;
        prow[i] = hn * fw;
    }
    // y partials: wave-local reduce over 64 s for rows rg*4..rg*4+3
#pragma unroll
    for (int i = 0; i < 4; ++i) {
        float v = prow[i];
#pragma unroll
        for (int off = 32; off; off >>= 1) v += __shfl_xor(v, off);
        if (lane == 0) y_part[(size_t)(m0 + rg * 4 + i) * 8 + n0] = v;
    }
    __syncthreads();

    // cua partial for t+1 over k-chunk [n0*64, n0*64+64) using fresh c (cs)
    if (t + 1 < NT) {
        int n = tid & 127, bg = tid >> 7;   // 4 groups x 8 rows
        float a8[8] = {0, 0, 0, 0, 0, 0, 0, 0};
        for (int k = 0; k < 64; ++k) {
            float ua = Ua[(size_t)(n0 * 64 + k) * (NT * NN) + (t + 1) * NN + n];
#pragma unroll
            for (int i = 0; i < 8; ++i) a8[i] += cs[bg * 8 + i][k] * ua;
        }
#pragma unroll
        for (int i = 0; i < 8; ++i)
            cua_part[((size_t)(m0 + bg * 8 + i) * 8 + n0) * 128 + n] = a8[i];
    }
}

// ---------------------------------------------------------------- final y (t = NT-1)
__global__ __launch_bounds__(256) void k_yfin(const float* __restrict__ y_part,
                                              const float* __restrict__ fcb,
                                              float* __restrict__ out_y) {
    int b = blockIdx.x * 256 + threadIdx.x;
    if (b < NB) {
        const float* yp = y_part + (size_t)b * 8;
        float yv = fcb[NT - 1];
#pragma unroll
        for (int p = 0; p < 8; ++p) yv += yp[p];
        out_y[b * NT + (NT - 1)] = yv;
    }
}

// ---------------------------------------------------------------- launcher
extern "C" void kernel_launch(void* const* d_in, const int* in_sizes, int n_in,
                              void* d_out, int out_size, void* d_ws, size_t ws_size,
                              hipStream_t stream) {
    (void)in_sizes; (void)n_in; (void)out_size; (void)ws_size;
    const float* H    = (const float*)d_in[0];
    const float* y0   = (const float*)d_in[1];
    const float* emb  = (const float*)d_in[2];
    const float* Wa   = (const float*)d_in[4];
    const float* Ua   = (const float*)d_in[5];
    const float* ba   = (const float*)d_in[6];
    const float* Va   = (const float*)d_in[7];
    const float* W    = (const float*)d_in[8];
    const float* U    = (const float*)d_in[9];
    const float* bias = (const float*)d_in[10];
    const float* Wy   = (const float*)d_in[11];
    const float* fcw  = (const float*)d_in[12];
    const float* fcb  = (const float*)d_in[13];

    float* out_y = (float*)d_out;              // (B, T)
    float* out_h = out_y + NB * NT;            // (B, T, HS)

    float* ws       = (float*)d_ws;
    float* c_st     = ws;                                   // B*HS
    float* y_st     = c_st + NB * NHS;                      // B
    float* y_part   = y_st + NB;                            // B*8
    float* cua_part = y_part + NB * 8;                      // B*8*128
    unsigned short* Hbf = (unsigned short*)(cua_part + NB * 8 * 128);  // BL*D
    unsigned short* Wab = Hbf + (size_t)BL * ND;            // T*N*D
    unsigned short* Ab0 = Wab + (size_t)NT * NN * ND;       // B*640
    unsigned short* Ab1 = Ab0 + (size_t)NB * NK;            // B*640
    unsigned short* Wg  = Ab1 + (size_t)NB * NK;            // T*10*2048*64

    hipLaunchKernelGGL(k_init, dim3((NB * NHS) / 256), dim3(256), 0, stream,
                       emb, y0, c_st, Ab0, y_st);
    hipLaunchKernelGGL(k_prep, dim3(BL * ND / (256 * 8)), dim3(256), 0, stream, H, Hbf);
    hipLaunchKernelGGL(k_prepwa, dim3(NT * NN), dim3(128), 0, stream, Wa, Wab);
    hipLaunchKernelGGL(k_prepw, dim3(32, 10, 24), dim3(256), 0, stream, W, U, Wg);
    hipLaunchKernelGGL(k_cua0, dim3(64, 8), dim3(256), 0, stream, c_st, Ua, cua_part);

    for (int t = 0; t < NT; ++t) {
        unsigned short* Ab  = (t & 1) ? Ab1 : Ab0;
        unsigned short* AbN = (t & 1) ? Ab0 : Ab1;
        hipLaunchKernelGGL(k_attn_fused, dim3(NB), dim3(384), 0, stream,
                           Hbf, Wab, Va, ba, cua_part, fcb, y_part, y_st, out_y, Ab, t);
        hipLaunchKernelGGL(k_gates_cell, dim3(32, 8), dim3(512), 0, stream,
                           Ab, AbN, Wg, bias, Wy, fcw, Ua, y_st, c_st,
                           out_h, y_part, cua_part, t);
    }
    hipLaunchKernelGGL(k_yfin, dim3(NB / 256), dim3(256), 0, stream, y_part, fcb, out_y);
}